// Round 16
// baseline (373.790 us; speedup 1.0000x reference)
//
#include <hip/hip_runtime.h>

// B=32768, S=3, D=512, F=512, H=8, DH=64
// Fused QKV proj + masked softmax attention (S=3) + out proj.
// Block = 16 batches = 48 rows; 8 waves = 8 heads; 512 threads.
// R16 = R15 + gemm unroll 1 -> 2 (both gemm_proj and gemm_proj2).
//       R15's K-split removed the register-peak coincidence that made
//       unroll 2 spill in R4/R5; every phase now peaks ~90 of 128 regs
//       at unroll 2, so the doubled b-load ILP should come for free.
//       LDS 80064 B -> 2 blocks/CU; launch_bounds(512,4).

typedef __bf16 bf16x8 __attribute__((ext_vector_type(8)));
typedef float f32x4 __attribute__((ext_vector_type(4)));

union U8 { bf16x8 v; unsigned short u[8]; unsigned int w[4]; uint4 q; };

__device__ __forceinline__ unsigned short f2bf(float f) {
  union { float f; unsigned int u; } v; v.f = f;
  unsigned int u = v.u;
  return (unsigned short)((u + 0x7FFFu + ((u >> 16) & 1u)) >> 16);  // RNE
}
__device__ __forceinline__ unsigned int cvt_pk_bf16(float lo, float hi) {
  unsigned int r;
  asm volatile("v_cvt_pk_bf16_f32 %0, %1, %2" : "=v"(r) : "v"(lo), "v"(hi));
  return r;  // [15:0]=bf16(lo), [31:16]=bf16(hi), RNE
}

// ---- kernel 0: W[k][n] fp32 -> bf16 fragment-ordered ----
// frag addr (shorts): ((n16*16 + ks)*64 + lane)*8 ; content B[n16*16+lr][ks*32+hi*8+e]
__global__ void __launch_bounds__(256) wtrans(const float* __restrict__ W0,
                                              const float* __restrict__ W1,
                                              const float* __restrict__ W2,
                                              const float* __restrict__ W3,
                                              unsigned short* __restrict__ out) {
  __shared__ float tile[64][65];
  const float* W = (blockIdx.z == 0) ? W0 : (blockIdx.z == 1) ? W1
                   : (blockIdx.z == 2) ? W2 : W3;
  unsigned short* O = out + (size_t)blockIdx.z * 512 * 512;
  int t = threadIdx.x;
  int k0 = blockIdx.x * 64, n0 = blockIdx.y * 64;
#pragma unroll
  for (int i = 0; i < 4; ++i) {
    int r = (t >> 4) + i * 16;
    int c = (t & 15) * 4;
    float4 v = *(const float4*)(W + (k0 + r) * 512 + n0 + c);
    tile[r][c] = v.x; tile[r][c + 1] = v.y; tile[r][c + 2] = v.z; tile[r][c + 3] = v.w;
  }
  __syncthreads();
  int lane = t & 63, f = t >> 6;
  int lr = lane & 15, hi = lane >> 4;
#pragma unroll
  for (int i = 0; i < 2; ++i) {
    int g = f + i * 4;          // 0..7
    int n16l = g & 3, ksl = g >> 2;
    U8 pk;
#pragma unroll
    for (int e = 0; e < 8; ++e)
      pk.u[e] = f2bf(tile[ksl * 32 + hi * 8 + e][n16l * 16 + lr]);
    int n16 = (n0 >> 4) + n16l;
    int ksg = (k0 >> 5) + ksl;
    *(uint4*)(O + (((n16 * 16 + ksg) * 64 + lane) * 8)) = pk.q;
  }
}

// ---------------- fused attention kernel ----------------
// LDS map (bytes):
//   [0     .. 49152)  shared buf [48][512] bf16 swizzled: q -> k -> v -> attn
//   [49152 .. 65536)  per-wave 2 KB tile scratch (16x64 bf16 / 48x20 bf16)
//   [65536 .. 71680)  per-wave score/P scratch [48][4] f32
//   [71680 .. 71872)  masks (48 ints)
//   [71872 .. 80064)  bias table f32 [4][512] (q,k,v,o)
#define SH_SCR  49152
#define SH_PS   65536
#define SH_MSK  71680
#define SH_BIAS 71872

__device__ __forceinline__ void stage48(const float* __restrict__ src, int row0,
                                        int t, char* smem) {
#pragma unroll 1
  for (int c = 0; c < 3; ++c) {
    float4 vals[4];
#pragma unroll
    for (int j = 0; j < 4; ++j) {
      int idx = t + (c * 4 + j) * 512;
      int row = idx >> 7, c4 = idx & 127;
      vals[j] = *(const float4*)(src + (size_t)(row0 + row) * 512 + c4 * 4);
    }
#pragma unroll
    for (int j = 0; j < 4; ++j) {
      int idx = t + (c * 4 + j) * 512;
      int row = idx >> 7, c4 = idx & 127;
      uint2 pk;
      pk.x = cvt_pk_bf16(vals[j].x, vals[j].y);
      pk.y = cvt_pk_bf16(vals[j].z, vals[j].w);
      *(uint2*)(smem + ((row * 1024 + c4 * 8) ^ ((row & 7) << 4))) = pk;
    }
  }
}

// full GEMM: 4 n16 tiles per wave (used for Q, V and O projections)
__device__ __forceinline__ void gemm_proj(const char* smem,
                                          const unsigned short* __restrict__ Bt,
                                          int w, int l, int lr, int lk8,
                                          f32x4 acc[3][4]) {
#pragma unroll 2
  for (int ks = 0; ks < 16; ++ks) {
    int kb = ks * 32 + lk8;
    bf16x8 a[3];
#pragma unroll
    for (int mt = 0; mt < 3; ++mt) {
      int row = mt * 16 + lr;
      a[mt] = *(const bf16x8*)(smem + ((row * 1024 + kb * 2) ^ ((row & 7) << 4)));
    }
#pragma unroll
    for (int np = 0; np < 2; ++np) {
      bf16x8 b[2];
#pragma unroll
      for (int j = 0; j < 2; ++j)
        b[j] = *(const bf16x8*)(Bt + (((w * 4 + np * 2 + j) * 16 + ks) * 64 + l) * 8);
#pragma unroll
      for (int j = 0; j < 2; ++j)
#pragma unroll
        for (int mt = 0; mt < 3; ++mt)
          acc[mt][np * 2 + j] =
              __builtin_amdgcn_mfma_f32_16x16x32_bf16(a[mt], b[j], acc[mt][np * 2 + j], 0, 0, 0);
    }
  }
}

// half GEMM: 2 n16 tiles (n16base, n16base+1); acc 24 regs
__device__ __forceinline__ void gemm_proj2(const char* smem,
                                           const unsigned short* __restrict__ Bt,
                                           int n16base, int l, int lr, int lk8,
                                           f32x4 acc[3][2]) {
#pragma unroll 2
  for (int ks = 0; ks < 16; ++ks) {
    int kb = ks * 32 + lk8;
    bf16x8 a[3];
#pragma unroll
    for (int mt = 0; mt < 3; ++mt) {
      int row = mt * 16 + lr;
      a[mt] = *(const bf16x8*)(smem + ((row * 1024 + kb * 2) ^ ((row & 7) << 4)));
    }
    bf16x8 b[2];
#pragma unroll
    for (int j = 0; j < 2; ++j)
      b[j] = *(const bf16x8*)(Bt + (((n16base + j) * 16 + ks) * 64 + l) * 8);
#pragma unroll
    for (int j = 0; j < 2; ++j)
#pragma unroll
      for (int mt = 0; mt < 3; ++mt)
        acc[mt][j] =
            __builtin_amdgcn_mfma_f32_16x16x32_bf16(a[mt], b[j], acc[mt][j], 0, 0, 0);
  }
}

// C-frag tile (16 rows x 64 cols) -> A-frag pair via per-wave 2 KB scratch.
__device__ __forceinline__ void tile_to_afrags(char* scr, const float* biasT, int bofs,
                                               const f32x4 acc[4], float scale,
                                               int lr, int hi, bf16x8* out) {
#pragma unroll
  for (int nt = 0; nt < 4; ++nt) {
    float bv = biasT[bofs + nt * 16];
#pragma unroll
    for (int r = 0; r < 4; ++r) {
      int row = 4 * hi + r;
      int col = nt * 16 + lr;
      int addr = (row * 128 + col * 2) ^ ((row & 7) << 4);
      *(unsigned short*)(scr + addr) = f2bf((acc[nt][r] + bv) * scale);
    }
  }
  asm volatile("s_waitcnt lgkmcnt(0)" ::: "memory");
#pragma unroll
  for (int kb = 0; kb < 2; ++kb) {
    int addr = (lr * 128 + (kb * 32 + hi * 8) * 2) ^ ((lr & 7) << 4);
    out[kb] = *(const bf16x8*)(scr + addr);
  }
  asm volatile("s_waitcnt lgkmcnt(0)" ::: "memory");
}

// half version: C-frag tile 16 rows x 32 cols (nt pair np) -> ONE A-frag (kb=np)
__device__ __forceinline__ void tile_to_afrag_half(char* scr, const float* biasT,
                                                   int bofs, const f32x4 acc2[2],
                                                   int np, int lr, int hi,
                                                   bf16x8* out1) {
#pragma unroll
  for (int j = 0; j < 2; ++j) {
    int nt = np * 2 + j;
    float bv = biasT[bofs + nt * 16];
#pragma unroll
    for (int r = 0; r < 4; ++r) {
      int row = 4 * hi + r;
      int col = nt * 16 + lr;
      int addr = (row * 128 + col * 2) ^ ((row & 7) << 4);
      *(unsigned short*)(scr + addr) = f2bf(acc2[j][r] + bv);
    }
  }
  asm volatile("s_waitcnt lgkmcnt(0)" ::: "memory");
  {
    int addr = (lr * 128 + (np * 32 + hi * 8) * 2) ^ ((lr & 7) << 4);
    *out1 = *(const bf16x8*)(scr + addr);
  }
  asm volatile("s_waitcnt lgkmcnt(0)" ::: "memory");
}

__global__ void __launch_bounds__(512, 4) fused_attn(
    const float* __restrict__ q, const float* __restrict__ kin, const float* __restrict__ vin,
    const int* __restrict__ mask, const unsigned short* __restrict__ wt,
    const float* __restrict__ bq, const float* __restrict__ bk,
    const float* __restrict__ bv, const float* __restrict__ bo,
    float* __restrict__ out) {
  __shared__ alignas(16) char smem[80064];
  const int t = threadIdx.x;
  const int w = t >> 6;            // wave id == head id
  const int l = t & 63;
  const int lr = l & 15;
  const int hi = l >> 4;
  const int lk8 = hi * 8;
  const int row0 = blockIdx.x * 48;
  const int batch0 = blockIdx.x * 16;
  char* scr = smem + SH_SCR + w * 2048;
  float* pscr = (float*)(smem + SH_PS + w * 768);
  int* maskb = (int*)(smem + SH_MSK);
  float* biasT = (float*)(smem + SH_BIAS);
  const int bidx = w * 64 + lr;    // per-lane bias column

  if (t < 48) maskb[t] = mask[batch0 * 3 + t];
  biasT[0 * 512 + t] = bq[t];
  biasT[1 * 512 + t] = bk[t];
  biasT[2 * 512 + t] = bv[t];
  biasT[3 * 512 + t] = bo[t];

  const unsigned short* Wtq = wt;
  const unsigned short* Wtk = wt + 512 * 512;
  const unsigned short* Wtv = wt + 2 * 512 * 512;
  const unsigned short* Wto = wt + 3 * 512 * 512;

  // ---- stage q, Q-proj, extract qh A-frags (scale 1/8, bias folded) ----
  stage48(q, row0, t, smem);
  __syncthreads();  // B1
  bf16x8 qa[3][2];
  {
    f32x4 aq[3][4] = {};
    gemm_proj(smem, Wtq, w, l, lr, lk8, aq);
#pragma unroll
    for (int mt = 0; mt < 3; ++mt)
      tile_to_afrags(scr, biasT, 0 * 512 + bidx, aq[mt], 0.125f, lr, hi, qa[mt]);
  }
  __syncthreads();  // B2: all waves done reading staged q

  // ---- stage k, K-proj in two nt-pair passes (ack peak 24 acc regs) ----
  stage48(kin, row0, t, smem);
  __syncthreads();  // B3
  {
    bf16x8 kf[3][2];
#pragma unroll
    for (int np = 0; np < 2; ++np) {
      f32x4 ack2[3][2] = {};
      gemm_proj2(smem, Wtk, w * 4 + np * 2, l, lr, lk8, ack2);
#pragma unroll
      for (int km = 0; km < 3; ++km)
        tile_to_afrag_half(scr, biasT, 1 * 512 + bidx, ack2[km], np, lr, hi,
                           &kf[km][np]);
    }

    // scores 48x48 (block-diagonal 3x3 kept), exact-fp32 reference mask math
#pragma unroll
    for (int km = 0; km < 3; ++km) {
      f32x4 s[3] = {};
#pragma unroll
      for (int qm = 0; qm < 3; ++qm) {
        s[qm] = __builtin_amdgcn_mfma_f32_16x16x32_bf16(qa[qm][0], kf[km][0], s[qm], 0, 0, 0);
        s[qm] = __builtin_amdgcn_mfma_f32_16x16x32_bf16(qa[qm][1], kf[km][1], s[qm], 0, 0, 0);
      }
#pragma unroll
      for (int qm = 0; qm < 3; ++qm)
#pragma unroll
        for (int r = 0; r < 4; ++r) {
          int qrow = qm * 16 + hi * 4 + r;
          int krow = km * 16 + lr;
          int qb = qrow / 3, kb2 = krow / 3;
          if (qb == kb2) pscr[qrow * 4 + (krow - kb2 * 3)] = s[qm][r];
        }
    }
    asm volatile("s_waitcnt lgkmcnt(0)" ::: "memory");
    // softmax per row; overwrite pscr with P (per-wave region, lgkm-ordered)
#pragma unroll
    for (int mt = 0; mt < 3; ++mt) {
      int row = mt * 16 + lr;
      int b = row / 3;
      int qi = row - b * 3;
      float s0 = pscr[row * 4 + 0], s1 = pscr[row * 4 + 1], s2 = pscr[row * 4 + 2];
      float m0 = (float)maskb[b * 3 + 0] * 1e9f;
      float m1 = (float)maskb[b * 3 + 1] * 1e9f;
      float m2 = (float)maskb[b * 3 + 2] * 1e9f;
      float mq = (qi == 0) ? m0 : (qi == 1) ? m1 : m2;
      float t0 = (s0 - m0) - mq;
      float t1 = (s1 - m1) - mq;
      float t2 = (s2 - m2) - mq;
      float mx = fmaxf(fmaxf(t0, t1), t2);
      float e0 = __expf(t0 - mx), e1 = __expf(t1 - mx), e2 = __expf(t2 - mx);
      float inv = 1.0f / (e0 + e1 + e2);
      asm volatile("s_waitcnt lgkmcnt(0)" ::: "memory");
      pscr[row * 4 + 0] = e0 * inv;
      pscr[row * 4 + 1] = e1 * inv;
      pscr[row * 4 + 2] = e2 * inv;
    }
  }
  __syncthreads();  // B4: all waves done reading staged k

  // ---- stage v, V-proj ----
  stage48(vin, row0, t, smem);
  __syncthreads();  // B5
  f32x4 acv[3][4] = {};
  gemm_proj(smem, Wtv, w, l, lr, lk8, acv);

  // P A-frags from LDS P-scratch: lane holds P[row=16mt+lr][k=32kb+8hi+e]
  bf16x8 pa[3][2];
#pragma unroll
  for (int mt = 0; mt < 3; ++mt) {
    int row = mt * 16 + lr;
    int b3 = (row / 3) * 3;
    float pr0 = pscr[row * 4 + 0];
    float pr1 = pscr[row * 4 + 1];
    float pr2 = pscr[row * 4 + 2];
#pragma unroll
    for (int kb = 0; kb < 2; ++kb) {
      U8 f;
#pragma unroll
      for (int e = 0; e < 8; ++e) {
        int k = kb * 32 + lk8 + e;
        int j = k - b3;
        float pv_ = (j == 0) ? pr0 : (j == 1) ? pr1 : (j == 2) ? pr2 : 0.f;
        f.u[e] = f2bf(pv_);
      }
      pa[mt][kb] = f.v;
    }
  }

  __syncthreads();  // B6: all waves done reading staged v (attn overwrite ok)

  // ---- per-nt vhT extraction + PV + attn write (acv dies as PV is computed) ----
#pragma unroll
  for (int nt = 0; nt < 4; ++nt) {
    float bvl = biasT[2 * 512 + bidx + nt * 16];
    // write vh[k][col=16nt+lr] for k=0..47 into per-wave scr [48][20] bf16
    // (40 B padded rows -> hi-groups hit bank sets {0-7},{8-15},{16-23},{24-31})
#pragma unroll
    for (int mt = 0; mt < 3; ++mt)
#pragma unroll
      for (int r = 0; r < 4; ++r) {
        int k = mt * 16 + hi * 4 + r;
        *(unsigned short*)(scr + k * 40 + lr * 2) = f2bf(acv[mt][nt][r] + bvl);
      }
    asm volatile("s_waitcnt lgkmcnt(0)" ::: "memory");
    // gather B-frags: vb[kb] = vh[32kb+8hi+e][lr]  (k>=48 -> pa is 0, any row ok)
    bf16x8 vb[2];
#pragma unroll
    for (int kb = 0; kb < 2; ++kb) {
      int base = (kb == 0) ? (8 * hi) * 40 : ((hi < 2) ? (32 + 8 * hi) * 40 : 0);
      U8 f;
#pragma unroll
      for (int e = 0; e < 8; ++e)
        f.u[e] = *(const unsigned short*)(scr + base + e * 40 + lr * 2);
      vb[kb] = f.v;
    }
    asm volatile("s_waitcnt lgkmcnt(0)" ::: "memory");
#pragma unroll
    for (int mt = 0; mt < 3; ++mt) {
      f32x4 po = {};
      po = __builtin_amdgcn_mfma_f32_16x16x32_bf16(pa[mt][0], vb[0], po, 0, 0, 0);
      po = __builtin_amdgcn_mfma_f32_16x16x32_bf16(pa[mt][1], vb[1], po, 0, 0, 0);
#pragma unroll
      for (int r = 0; r < 4; ++r) {
        int row = mt * 16 + hi * 4 + r;
        int col = w * 64 + nt * 16 + lr;
        *(unsigned short*)(smem + ((row * 1024 + col * 2) ^ ((row & 7) << 4))) =
            f2bf(po[r]);
      }
    }
  }
  __syncthreads();  // B7: attn ready

  // ---- out = attn @ Wo + bo ----
  f32x4 ao[3][4] = {};
  gemm_proj(smem, Wto, w, l, lr, lk8, ao);
#pragma unroll
  for (int mt = 0; mt < 3; ++mt)
#pragma unroll
    for (int nt = 0; nt < 4; ++nt) {
      float bvo = biasT[3 * 512 + bidx + nt * 16];
#pragma unroll
      for (int r = 0; r < 4; ++r) {
        int grow = row0 + mt * 16 + hi * 4 + r;
        int col = w * 64 + nt * 16 + lr;
        out[(size_t)grow * 512 + col] = ao[mt][nt][r] + bvo;
      }
    }
}

extern "C" void kernel_launch(void* const* d_in, const int* in_sizes, int n_in,
                              void* d_out, int out_size, void* d_ws, size_t ws_size,
                              hipStream_t stream) {
  const float* q = (const float*)d_in[0];
  const float* k = (const float*)d_in[1];
  const float* v = (const float*)d_in[2];
  const int* mask = (const int*)d_in[3];
  const float* Wq = (const float*)d_in[4];
  const float* bq = (const float*)d_in[5];
  const float* Wk = (const float*)d_in[6];
  const float* bk = (const float*)d_in[7];
  const float* Wv = (const float*)d_in[8];
  const float* bv = (const float*)d_in[9];
  const float* Wo = (const float*)d_in[10];
  const float* bo = (const float*)d_in[11];
  float* out = (float*)d_out;
  unsigned short* wt = (unsigned short*)d_ws;  // 4 x 512x512 bf16 = 2 MB

  wtrans<<<dim3(8, 8, 4), 256, 0, stream>>>(Wq, Wk, Wv, Wo, wt);
  fused_attn<<<2048, 512, 0, stream>>>(q, k, v, mask, wt, bq, bk, bv, bo, out);
}

// Round 17
// 360.039 us; speedup vs baseline: 1.0382x; 1.0382x over previous
//
#include <hip/hip_runtime.h>

// B=32768, S=3, D=512, F=512, H=8, DH=64
// Fused QKV proj + masked softmax attention (S=3) + out proj.
// Block = 16 batches = 48 rows; 8 waves = 8 heads; 512 threads.
// R17 = R15 (unroll 1, K-split) + PV-path vectorization:
//       - vh scratch column-major [16 lr][48 k] (112B cols): writes
//         2 cvt_pk + ds_write_b64 per mt, vb gather = 1 ds_read_b128/kb.
//       - pa built from 3 pre-converted bf16 shorts (saves ~45 f2bf).
//       LDS 80064 B -> 2 blocks/CU; launch_bounds(512,4).

typedef __bf16 bf16x8 __attribute__((ext_vector_type(8)));
typedef float f32x4 __attribute__((ext_vector_type(4)));

union U8 { bf16x8 v; unsigned short u[8]; unsigned int w[4]; uint4 q; };

__device__ __forceinline__ unsigned short f2bf(float f) {
  union { float f; unsigned int u; } v; v.f = f;
  unsigned int u = v.u;
  return (unsigned short)((u + 0x7FFFu + ((u >> 16) & 1u)) >> 16);  // RNE
}
__device__ __forceinline__ unsigned int cvt_pk_bf16(float lo, float hi) {
  unsigned int r;
  asm volatile("v_cvt_pk_bf16_f32 %0, %1, %2" : "=v"(r) : "v"(lo), "v"(hi));
  return r;  // [15:0]=bf16(lo), [31:16]=bf16(hi), RNE
}

// ---- kernel 0: W[k][n] fp32 -> bf16 fragment-ordered ----
// frag addr (shorts): ((n16*16 + ks)*64 + lane)*8 ; content B[n16*16+lr][ks*32+hi*8+e]
__global__ void __launch_bounds__(256) wtrans(const float* __restrict__ W0,
                                              const float* __restrict__ W1,
                                              const float* __restrict__ W2,
                                              const float* __restrict__ W3,
                                              unsigned short* __restrict__ out) {
  __shared__ float tile[64][65];
  const float* W = (blockIdx.z == 0) ? W0 : (blockIdx.z == 1) ? W1
                   : (blockIdx.z == 2) ? W2 : W3;
  unsigned short* O = out + (size_t)blockIdx.z * 512 * 512;
  int t = threadIdx.x;
  int k0 = blockIdx.x * 64, n0 = blockIdx.y * 64;
#pragma unroll
  for (int i = 0; i < 4; ++i) {
    int r = (t >> 4) + i * 16;
    int c = (t & 15) * 4;
    float4 v = *(const float4*)(W + (k0 + r) * 512 + n0 + c);
    tile[r][c] = v.x; tile[r][c + 1] = v.y; tile[r][c + 2] = v.z; tile[r][c + 3] = v.w;
  }
  __syncthreads();
  int lane = t & 63, f = t >> 6;
  int lr = lane & 15, hi = lane >> 4;
#pragma unroll
  for (int i = 0; i < 2; ++i) {
    int g = f + i * 4;          // 0..7
    int n16l = g & 3, ksl = g >> 2;
    U8 pk;
#pragma unroll
    for (int e = 0; e < 8; ++e)
      pk.u[e] = f2bf(tile[ksl * 32 + hi * 8 + e][n16l * 16 + lr]);
    int n16 = (n0 >> 4) + n16l;
    int ksg = (k0 >> 5) + ksl;
    *(uint4*)(O + (((n16 * 16 + ksg) * 64 + lane) * 8)) = pk.q;
  }
}

// ---------------- fused attention kernel ----------------
// LDS map (bytes):
//   [0     .. 49152)  shared buf [48][512] bf16 swizzled: q -> k -> v -> attn
//   [49152 .. 65536)  per-wave 2 KB tile scratch (16x64 frag / [16][48] vh)
//   [65536 .. 71680)  per-wave score/P scratch [48][4] f32
//   [71680 .. 71872)  masks (48 ints)
//   [71872 .. 80064)  bias table f32 [4][512] (q,k,v,o)
#define SH_SCR  49152
#define SH_PS   65536
#define SH_MSK  71680
#define SH_BIAS 71872

__device__ __forceinline__ void stage48(const float* __restrict__ src, int row0,
                                        int t, char* smem) {
#pragma unroll 1
  for (int c = 0; c < 3; ++c) {
    float4 vals[4];
#pragma unroll
    for (int j = 0; j < 4; ++j) {
      int idx = t + (c * 4 + j) * 512;
      int row = idx >> 7, c4 = idx & 127;
      vals[j] = *(const float4*)(src + (size_t)(row0 + row) * 512 + c4 * 4);
    }
#pragma unroll
    for (int j = 0; j < 4; ++j) {
      int idx = t + (c * 4 + j) * 512;
      int row = idx >> 7, c4 = idx & 127;
      uint2 pk;
      pk.x = cvt_pk_bf16(vals[j].x, vals[j].y);
      pk.y = cvt_pk_bf16(vals[j].z, vals[j].w);
      *(uint2*)(smem + ((row * 1024 + c4 * 8) ^ ((row & 7) << 4))) = pk;
    }
  }
}

// full GEMM: 4 n16 tiles per wave (used for Q, V and O projections)
__device__ __forceinline__ void gemm_proj(const char* smem,
                                          const unsigned short* __restrict__ Bt,
                                          int w, int l, int lr, int lk8,
                                          f32x4 acc[3][4]) {
#pragma unroll 1
  for (int ks = 0; ks < 16; ++ks) {
    int kb = ks * 32 + lk8;
    bf16x8 a[3];
#pragma unroll
    for (int mt = 0; mt < 3; ++mt) {
      int row = mt * 16 + lr;
      a[mt] = *(const bf16x8*)(smem + ((row * 1024 + kb * 2) ^ ((row & 7) << 4)));
    }
#pragma unroll
    for (int np = 0; np < 2; ++np) {
      bf16x8 b[2];
#pragma unroll
      for (int j = 0; j < 2; ++j)
        b[j] = *(const bf16x8*)(Bt + (((w * 4 + np * 2 + j) * 16 + ks) * 64 + l) * 8);
#pragma unroll
      for (int j = 0; j < 2; ++j)
#pragma unroll
        for (int mt = 0; mt < 3; ++mt)
          acc[mt][np * 2 + j] =
              __builtin_amdgcn_mfma_f32_16x16x32_bf16(a[mt], b[j], acc[mt][np * 2 + j], 0, 0, 0);
    }
  }
}

// half GEMM: 2 n16 tiles (n16base, n16base+1); acc 24 regs
__device__ __forceinline__ void gemm_proj2(const char* smem,
                                           const unsigned short* __restrict__ Bt,
                                           int n16base, int l, int lr, int lk8,
                                           f32x4 acc[3][2]) {
#pragma unroll 1
  for (int ks = 0; ks < 16; ++ks) {
    int kb = ks * 32 + lk8;
    bf16x8 a[3];
#pragma unroll
    for (int mt = 0; mt < 3; ++mt) {
      int row = mt * 16 + lr;
      a[mt] = *(const bf16x8*)(smem + ((row * 1024 + kb * 2) ^ ((row & 7) << 4)));
    }
    bf16x8 b[2];
#pragma unroll
    for (int j = 0; j < 2; ++j)
      b[j] = *(const bf16x8*)(Bt + (((n16base + j) * 16 + ks) * 64 + l) * 8);
#pragma unroll
    for (int j = 0; j < 2; ++j)
#pragma unroll
      for (int mt = 0; mt < 3; ++mt)
        acc[mt][j] =
            __builtin_amdgcn_mfma_f32_16x16x32_bf16(a[mt], b[j], acc[mt][j], 0, 0, 0);
  }
}

// C-frag tile (16 rows x 64 cols) -> A-frag pair via per-wave 2 KB scratch.
__device__ __forceinline__ void tile_to_afrags(char* scr, const float* biasT, int bofs,
                                               const f32x4 acc[4], float scale,
                                               int lr, int hi, bf16x8* out) {
#pragma unroll
  for (int nt = 0; nt < 4; ++nt) {
    float bv = biasT[bofs + nt * 16];
#pragma unroll
    for (int r = 0; r < 4; ++r) {
      int row = 4 * hi + r;
      int col = nt * 16 + lr;
      int addr = (row * 128 + col * 2) ^ ((row & 7) << 4);
      *(unsigned short*)(scr + addr) = f2bf((acc[nt][r] + bv) * scale);
    }
  }
  asm volatile("s_waitcnt lgkmcnt(0)" ::: "memory");
#pragma unroll
  for (int kb = 0; kb < 2; ++kb) {
    int addr = (lr * 128 + (kb * 32 + hi * 8) * 2) ^ ((lr & 7) << 4);
    out[kb] = *(const bf16x8*)(scr + addr);
  }
  asm volatile("s_waitcnt lgkmcnt(0)" ::: "memory");
}

// half version: C-frag tile 16 rows x 32 cols (nt pair np) -> ONE A-frag (kb=np)
__device__ __forceinline__ void tile_to_afrag_half(char* scr, const float* biasT,
                                                   int bofs, const f32x4 acc2[2],
                                                   int np, int lr, int hi,
                                                   bf16x8* out1) {
#pragma unroll
  for (int j = 0; j < 2; ++j) {
    int nt = np * 2 + j;
    float bv = biasT[bofs + nt * 16];
#pragma unroll
    for (int r = 0; r < 4; ++r) {
      int row = 4 * hi + r;
      int col = nt * 16 + lr;
      int addr = (row * 128 + col * 2) ^ ((row & 7) << 4);
      *(unsigned short*)(scr + addr) = f2bf(acc2[j][r] + bv);
    }
  }
  asm volatile("s_waitcnt lgkmcnt(0)" ::: "memory");
  {
    int addr = (lr * 128 + (np * 32 + hi * 8) * 2) ^ ((lr & 7) << 4);
    *out1 = *(const bf16x8*)(scr + addr);
  }
  asm volatile("s_waitcnt lgkmcnt(0)" ::: "memory");
}

__global__ void __launch_bounds__(512, 4) fused_attn(
    const float* __restrict__ q, const float* __restrict__ kin, const float* __restrict__ vin,
    const int* __restrict__ mask, const unsigned short* __restrict__ wt,
    const float* __restrict__ bq, const float* __restrict__ bk,
    const float* __restrict__ bv, const float* __restrict__ bo,
    float* __restrict__ out) {
  __shared__ alignas(16) char smem[80064];
  const int t = threadIdx.x;
  const int w = t >> 6;            // wave id == head id
  const int l = t & 63;
  const int lr = l & 15;
  const int hi = l >> 4;
  const int lk8 = hi * 8;
  const int row0 = blockIdx.x * 48;
  const int batch0 = blockIdx.x * 16;
  char* scr = smem + SH_SCR + w * 2048;
  float* pscr = (float*)(smem + SH_PS + w * 768);
  int* maskb = (int*)(smem + SH_MSK);
  float* biasT = (float*)(smem + SH_BIAS);
  const int bidx = w * 64 + lr;    // per-lane bias column

  if (t < 48) maskb[t] = mask[batch0 * 3 + t];
  biasT[0 * 512 + t] = bq[t];
  biasT[1 * 512 + t] = bk[t];
  biasT[2 * 512 + t] = bv[t];
  biasT[3 * 512 + t] = bo[t];

  const unsigned short* Wtq = wt;
  const unsigned short* Wtk = wt + 512 * 512;
  const unsigned short* Wtv = wt + 2 * 512 * 512;
  const unsigned short* Wto = wt + 3 * 512 * 512;

  // ---- stage q, Q-proj, extract qh A-frags (scale 1/8, bias folded) ----
  stage48(q, row0, t, smem);
  __syncthreads();  // B1
  bf16x8 qa[3][2];
  {
    f32x4 aq[3][4] = {};
    gemm_proj(smem, Wtq, w, l, lr, lk8, aq);
#pragma unroll
    for (int mt = 0; mt < 3; ++mt)
      tile_to_afrags(scr, biasT, 0 * 512 + bidx, aq[mt], 0.125f, lr, hi, qa[mt]);
  }
  __syncthreads();  // B2: all waves done reading staged q

  // ---- stage k, K-proj in two nt-pair passes (ack peak 24 acc regs) ----
  stage48(kin, row0, t, smem);
  __syncthreads();  // B3
  {
    bf16x8 kf[3][2];
#pragma unroll
    for (int np = 0; np < 2; ++np) {
      f32x4 ack2[3][2] = {};
      gemm_proj2(smem, Wtk, w * 4 + np * 2, l, lr, lk8, ack2);
#pragma unroll
      for (int km = 0; km < 3; ++km)
        tile_to_afrag_half(scr, biasT, 1 * 512 + bidx, ack2[km], np, lr, hi,
                           &kf[km][np]);
    }

    // scores 48x48 (block-diagonal 3x3 kept), exact-fp32 reference mask math
#pragma unroll
    for (int km = 0; km < 3; ++km) {
      f32x4 s[3] = {};
#pragma unroll
      for (int qm = 0; qm < 3; ++qm) {
        s[qm] = __builtin_amdgcn_mfma_f32_16x16x32_bf16(qa[qm][0], kf[km][0], s[qm], 0, 0, 0);
        s[qm] = __builtin_amdgcn_mfma_f32_16x16x32_bf16(qa[qm][1], kf[km][1], s[qm], 0, 0, 0);
      }
#pragma unroll
      for (int qm = 0; qm < 3; ++qm)
#pragma unroll
        for (int r = 0; r < 4; ++r) {
          int qrow = qm * 16 + hi * 4 + r;
          int krow = km * 16 + lr;
          int qb = qrow / 3, kb2 = krow / 3;
          if (qb == kb2) pscr[qrow * 4 + (krow - kb2 * 3)] = s[qm][r];
        }
    }
    asm volatile("s_waitcnt lgkmcnt(0)" ::: "memory");
    // softmax per row; overwrite pscr with P (per-wave region, lgkm-ordered)
#pragma unroll
    for (int mt = 0; mt < 3; ++mt) {
      int row = mt * 16 + lr;
      int b = row / 3;
      int qi = row - b * 3;
      float s0 = pscr[row * 4 + 0], s1 = pscr[row * 4 + 1], s2 = pscr[row * 4 + 2];
      float m0 = (float)maskb[b * 3 + 0] * 1e9f;
      float m1 = (float)maskb[b * 3 + 1] * 1e9f;
      float m2 = (float)maskb[b * 3 + 2] * 1e9f;
      float mq = (qi == 0) ? m0 : (qi == 1) ? m1 : m2;
      float t0 = (s0 - m0) - mq;
      float t1 = (s1 - m1) - mq;
      float t2 = (s2 - m2) - mq;
      float mx = fmaxf(fmaxf(t0, t1), t2);
      float e0 = __expf(t0 - mx), e1 = __expf(t1 - mx), e2 = __expf(t2 - mx);
      float inv = 1.0f / (e0 + e1 + e2);
      asm volatile("s_waitcnt lgkmcnt(0)" ::: "memory");
      pscr[row * 4 + 0] = e0 * inv;
      pscr[row * 4 + 1] = e1 * inv;
      pscr[row * 4 + 2] = e2 * inv;
    }
  }
  __syncthreads();  // B4: all waves done reading staged k

  // ---- stage v, V-proj ----
  stage48(vin, row0, t, smem);
  __syncthreads();  // B5
  f32x4 acv[3][4] = {};
  gemm_proj(smem, Wtv, w, l, lr, lk8, acv);

  // P A-frags: convert P once to bf16 shorts, then select (no per-elem f2bf)
  bf16x8 pa[3][2];
#pragma unroll
  for (int mt = 0; mt < 3; ++mt) {
    int row = mt * 16 + lr;
    int b3 = (row / 3) * 3;
    unsigned short pb0 = f2bf(pscr[row * 4 + 0]);
    unsigned short pb1 = f2bf(pscr[row * 4 + 1]);
    unsigned short pb2 = f2bf(pscr[row * 4 + 2]);
#pragma unroll
    for (int kb = 0; kb < 2; ++kb) {
      U8 f;
#pragma unroll
      for (int e = 0; e < 8; ++e) {
        int k = kb * 32 + lk8 + e;
        int j = k - b3;
        f.u[e] = (j == 0) ? pb0 : (j == 1) ? pb1 : (j == 2) ? pb2 : (unsigned short)0;
      }
      pa[mt][kb] = f.v;
    }
  }

  __syncthreads();  // B6: all waves done reading staged v (attn overwrite ok)

  // ---- per-nt vhT extraction (col-major, packed) + PV + attn write ----
  // vh scratch: [16 lr-cols][48 k] bf16, 112 B per column (16B aligned).
#pragma unroll
  for (int nt = 0; nt < 4; ++nt) {
    float bvl = biasT[2 * 512 + bidx + nt * 16];
    // write vh[k=mt*16+hi*4+{0..3}][col=lr]: one packed b64 per mt
#pragma unroll
    for (int mt = 0; mt < 3; ++mt) {
      uint2 pk;
      pk.x = cvt_pk_bf16(acv[mt][nt][0] + bvl, acv[mt][nt][1] + bvl);
      pk.y = cvt_pk_bf16(acv[mt][nt][2] + bvl, acv[mt][nt][3] + bvl);
      *(uint2*)(scr + lr * 112 + mt * 32 + hi * 8) = pk;
    }
    asm volatile("s_waitcnt lgkmcnt(0)" ::: "memory");
    // gather B-frags: vb[kb] = vh[32kb+8hi+e][lr], e contiguous -> b128
    // (kb=1, hi>=2 -> k>=48: redirect to offset 0; pa is 0 there)
    bf16x8 vb[2];
    vb[0] = *(const bf16x8*)(scr + lr * 112 + hi * 16);
    {
      int off1 = (hi < 2) ? (64 + hi * 16) : 0;
      vb[1] = *(const bf16x8*)(scr + lr * 112 + off1);
    }
    asm volatile("s_waitcnt lgkmcnt(0)" ::: "memory");
#pragma unroll
    for (int mt = 0; mt < 3; ++mt) {
      f32x4 po = {};
      po = __builtin_amdgcn_mfma_f32_16x16x32_bf16(pa[mt][0], vb[0], po, 0, 0, 0);
      po = __builtin_amdgcn_mfma_f32_16x16x32_bf16(pa[mt][1], vb[1], po, 0, 0, 0);
#pragma unroll
      for (int r = 0; r < 4; ++r) {
        int row = mt * 16 + hi * 4 + r;
        int col = w * 64 + nt * 16 + lr;
        *(unsigned short*)(smem + ((row * 1024 + col * 2) ^ ((row & 7) << 4))) =
            f2bf(po[r]);
      }
    }
  }
  __syncthreads();  // B7: attn ready

  // ---- out = attn @ Wo + bo ----
  f32x4 ao[3][4] = {};
  gemm_proj(smem, Wto, w, l, lr, lk8, ao);
#pragma unroll
  for (int mt = 0; mt < 3; ++mt)
#pragma unroll
    for (int nt = 0; nt < 4; ++nt) {
      float bvo = biasT[3 * 512 + bidx + nt * 16];
#pragma unroll
      for (int r = 0; r < 4; ++r) {
        int grow = row0 + mt * 16 + hi * 4 + r;
        int col = w * 64 + nt * 16 + lr;
        out[(size_t)grow * 512 + col] = ao[mt][nt][r] + bvo;
      }
    }
}

extern "C" void kernel_launch(void* const* d_in, const int* in_sizes, int n_in,
                              void* d_out, int out_size, void* d_ws, size_t ws_size,
                              hipStream_t stream) {
  const float* q = (const float*)d_in[0];
  const float* k = (const float*)d_in[1];
  const float* v = (const float*)d_in[2];
  const int* mask = (const int*)d_in[3];
  const float* Wq = (const float*)d_in[4];
  const float* bq = (const float*)d_in[5];
  const float* Wk = (const float*)d_in[6];
  const float* bk = (const float*)d_in[7];
  const float* Wv = (const float*)d_in[8];
  const float* bv = (const float*)d_in[9];
  const float* Wo = (const float*)d_in[10];
  const float* bo = (const float*)d_in[11];
  float* out = (float*)d_out;
  unsigned short* wt = (unsigned short*)d_ws;  // 4 x 512x512 bf16 = 2 MB

  wtrans<<<dim3(8, 8, 4), 256, 0, stream>>>(Wq, Wk, Wv, Wo, wt);
  fused_attn<<<2048, 512, 0, stream>>>(q, k, v, mask, wt, bq, bk, bv, bo, out);
}

// Round 18
// 353.798 us; speedup vs baseline: 1.0565x; 1.0176x over previous
//
#include <hip/hip_runtime.h>

// B=32768, S=3, D=512, F=512, H=8, DH=64
// Fused QKV proj + masked softmax attention (S=3) + out proj.
// Block = 16 batches = 48 rows; 8 waves = 8 heads; 512 threads.
// R18 = R17 + bias folded into MFMA accumulator init (C-frag col is
//       constant per lane -> acc init = bias, all +bias adds deleted)
//       + 0.125 score scale folded into wtrans(Wq) and bq (exact /8).
//       LDS 80064 B -> 2 blocks/CU; launch_bounds(512,4).

typedef __bf16 bf16x8 __attribute__((ext_vector_type(8)));
typedef float f32x4 __attribute__((ext_vector_type(4)));

union U8 { bf16x8 v; unsigned short u[8]; unsigned int w[4]; uint4 q; };

__device__ __forceinline__ unsigned short f2bf(float f) {
  union { float f; unsigned int u; } v; v.f = f;
  unsigned int u = v.u;
  return (unsigned short)((u + 0x7FFFu + ((u >> 16) & 1u)) >> 16);  // RNE
}
__device__ __forceinline__ unsigned int cvt_pk_bf16(float lo, float hi) {
  unsigned int r;
  asm volatile("v_cvt_pk_bf16_f32 %0, %1, %2" : "=v"(r) : "v"(lo), "v"(hi));
  return r;  // [15:0]=bf16(lo), [31:16]=bf16(hi), RNE
}

// ---- kernel 0: W[k][n] fp32 -> bf16 fragment-ordered (Wq pre-scaled /8) ----
// frag addr (shorts): ((n16*16 + ks)*64 + lane)*8 ; content B[n16*16+lr][ks*32+hi*8+e]
__global__ void __launch_bounds__(256) wtrans(const float* __restrict__ W0,
                                              const float* __restrict__ W1,
                                              const float* __restrict__ W2,
                                              const float* __restrict__ W3,
                                              unsigned short* __restrict__ out) {
  __shared__ float tile[64][65];
  const float* W = (blockIdx.z == 0) ? W0 : (blockIdx.z == 1) ? W1
                   : (blockIdx.z == 2) ? W2 : W3;
  const float scl = (blockIdx.z == 0) ? 0.125f : 1.0f;
  unsigned short* O = out + (size_t)blockIdx.z * 512 * 512;
  int t = threadIdx.x;
  int k0 = blockIdx.x * 64, n0 = blockIdx.y * 64;
#pragma unroll
  for (int i = 0; i < 4; ++i) {
    int r = (t >> 4) + i * 16;
    int c = (t & 15) * 4;
    float4 v = *(const float4*)(W + (k0 + r) * 512 + n0 + c);
    tile[r][c] = v.x; tile[r][c + 1] = v.y; tile[r][c + 2] = v.z; tile[r][c + 3] = v.w;
  }
  __syncthreads();
  int lane = t & 63, f = t >> 6;
  int lr = lane & 15, hi = lane >> 4;
#pragma unroll
  for (int i = 0; i < 2; ++i) {
    int g = f + i * 4;          // 0..7
    int n16l = g & 3, ksl = g >> 2;
    U8 pk;
#pragma unroll
    for (int e = 0; e < 8; ++e)
      pk.u[e] = f2bf(tile[ksl * 32 + hi * 8 + e][n16l * 16 + lr] * scl);
    int n16 = (n0 >> 4) + n16l;
    int ksg = (k0 >> 5) + ksl;
    *(uint4*)(O + (((n16 * 16 + ksg) * 64 + lane) * 8)) = pk.q;
  }
}

// ---------------- fused attention kernel ----------------
// LDS map (bytes):
//   [0     .. 49152)  shared buf [48][512] bf16 swizzled: q -> k -> v -> attn
//   [49152 .. 65536)  per-wave 2 KB tile scratch (16x64 frag / [16][48] vh)
//   [65536 .. 71680)  per-wave score/P scratch [48][4] f32
//   [71680 .. 71872)  masks (48 ints)
//   [71872 .. 80064)  bias table f32 [4][512] (q/8,k,v,o)
#define SH_SCR  49152
#define SH_PS   65536
#define SH_MSK  71680
#define SH_BIAS 71872

__device__ __forceinline__ void stage48(const float* __restrict__ src, int row0,
                                        int t, char* smem) {
#pragma unroll 1
  for (int c = 0; c < 3; ++c) {
    float4 vals[4];
#pragma unroll
    for (int j = 0; j < 4; ++j) {
      int idx = t + (c * 4 + j) * 512;
      int row = idx >> 7, c4 = idx & 127;
      vals[j] = *(const float4*)(src + (size_t)(row0 + row) * 512 + c4 * 4);
    }
#pragma unroll
    for (int j = 0; j < 4; ++j) {
      int idx = t + (c * 4 + j) * 512;
      int row = idx >> 7, c4 = idx & 127;
      uint2 pk;
      pk.x = cvt_pk_bf16(vals[j].x, vals[j].y);
      pk.y = cvt_pk_bf16(vals[j].z, vals[j].w);
      *(uint2*)(smem + ((row * 1024 + c4 * 8) ^ ((row & 7) << 4))) = pk;
    }
  }
}

// full GEMM: 4 n16 tiles per wave; acc pre-initialized by caller (bias fold)
__device__ __forceinline__ void gemm_proj(const char* smem,
                                          const unsigned short* __restrict__ Bt,
                                          int w, int l, int lr, int lk8,
                                          f32x4 acc[3][4]) {
#pragma unroll 1
  for (int ks = 0; ks < 16; ++ks) {
    int kb = ks * 32 + lk8;
    bf16x8 a[3];
#pragma unroll
    for (int mt = 0; mt < 3; ++mt) {
      int row = mt * 16 + lr;
      a[mt] = *(const bf16x8*)(smem + ((row * 1024 + kb * 2) ^ ((row & 7) << 4)));
    }
#pragma unroll
    for (int np = 0; np < 2; ++np) {
      bf16x8 b[2];
#pragma unroll
      for (int j = 0; j < 2; ++j)
        b[j] = *(const bf16x8*)(Bt + (((w * 4 + np * 2 + j) * 16 + ks) * 64 + l) * 8);
#pragma unroll
      for (int j = 0; j < 2; ++j)
#pragma unroll
        for (int mt = 0; mt < 3; ++mt)
          acc[mt][np * 2 + j] =
              __builtin_amdgcn_mfma_f32_16x16x32_bf16(a[mt], b[j], acc[mt][np * 2 + j], 0, 0, 0);
    }
  }
}

// half GEMM: 2 n16 tiles (n16base, n16base+1); acc 24 regs, pre-initialized
__device__ __forceinline__ void gemm_proj2(const char* smem,
                                           const unsigned short* __restrict__ Bt,
                                           int n16base, int l, int lr, int lk8,
                                           f32x4 acc[3][2]) {
#pragma unroll 1
  for (int ks = 0; ks < 16; ++ks) {
    int kb = ks * 32 + lk8;
    bf16x8 a[3];
#pragma unroll
    for (int mt = 0; mt < 3; ++mt) {
      int row = mt * 16 + lr;
      a[mt] = *(const bf16x8*)(smem + ((row * 1024 + kb * 2) ^ ((row & 7) << 4)));
    }
    bf16x8 b[2];
#pragma unroll
    for (int j = 0; j < 2; ++j)
      b[j] = *(const bf16x8*)(Bt + (((n16base + j) * 16 + ks) * 64 + l) * 8);
#pragma unroll
    for (int j = 0; j < 2; ++j)
#pragma unroll
      for (int mt = 0; mt < 3; ++mt)
        acc[mt][j] =
            __builtin_amdgcn_mfma_f32_16x16x32_bf16(a[mt], b[j], acc[mt][j], 0, 0, 0);
  }
}

// C-frag tile (16 rows x 64 cols, bias already in acc) -> A-frag pair.
__device__ __forceinline__ void tile_to_afrags(char* scr, const f32x4 acc[4],
                                               int lr, int hi, bf16x8* out) {
#pragma unroll
  for (int nt = 0; nt < 4; ++nt) {
#pragma unroll
    for (int r = 0; r < 4; ++r) {
      int row = 4 * hi + r;
      int col = nt * 16 + lr;
      int addr = (row * 128 + col * 2) ^ ((row & 7) << 4);
      *(unsigned short*)(scr + addr) = f2bf(acc[nt][r]);
    }
  }
  asm volatile("s_waitcnt lgkmcnt(0)" ::: "memory");
#pragma unroll
  for (int kb = 0; kb < 2; ++kb) {
    int addr = (lr * 128 + (kb * 32 + hi * 8) * 2) ^ ((lr & 7) << 4);
    out[kb] = *(const bf16x8*)(scr + addr);
  }
  asm volatile("s_waitcnt lgkmcnt(0)" ::: "memory");
}

// half version: C-frag tile 16 rows x 32 cols (nt pair np) -> ONE A-frag (kb=np)
__device__ __forceinline__ void tile_to_afrag_half(char* scr, const f32x4 acc2[2],
                                                   int np, int lr, int hi,
                                                   bf16x8* out1) {
#pragma unroll
  for (int j = 0; j < 2; ++j) {
    int nt = np * 2 + j;
#pragma unroll
    for (int r = 0; r < 4; ++r) {
      int row = 4 * hi + r;
      int col = nt * 16 + lr;
      int addr = (row * 128 + col * 2) ^ ((row & 7) << 4);
      *(unsigned short*)(scr + addr) = f2bf(acc2[j][r]);
    }
  }
  asm volatile("s_waitcnt lgkmcnt(0)" ::: "memory");
  {
    int addr = (lr * 128 + (np * 32 + hi * 8) * 2) ^ ((lr & 7) << 4);
    *out1 = *(const bf16x8*)(scr + addr);
  }
  asm volatile("s_waitcnt lgkmcnt(0)" ::: "memory");
}

__global__ void __launch_bounds__(512, 4) fused_attn(
    const float* __restrict__ q, const float* __restrict__ kin, const float* __restrict__ vin,
    const int* __restrict__ mask, const unsigned short* __restrict__ wt,
    const float* __restrict__ bq, const float* __restrict__ bk,
    const float* __restrict__ bv, const float* __restrict__ bo,
    float* __restrict__ out) {
  __shared__ alignas(16) char smem[80064];
  const int t = threadIdx.x;
  const int w = t >> 6;            // wave id == head id
  const int l = t & 63;
  const int lr = l & 15;
  const int hi = l >> 4;
  const int lk8 = hi * 8;
  const int row0 = blockIdx.x * 48;
  const int batch0 = blockIdx.x * 16;
  char* scr = smem + SH_SCR + w * 2048;
  float* pscr = (float*)(smem + SH_PS + w * 768);
  int* maskb = (int*)(smem + SH_MSK);
  float* biasT = (float*)(smem + SH_BIAS);
  const int bidx = w * 64 + lr;    // per-lane bias column

  if (t < 48) maskb[t] = mask[batch0 * 3 + t];
  biasT[0 * 512 + t] = bq[t] * 0.125f;   // scale folded (exact /8)
  biasT[1 * 512 + t] = bk[t];
  biasT[2 * 512 + t] = bv[t];
  biasT[3 * 512 + t] = bo[t];

  const unsigned short* Wtq = wt;
  const unsigned short* Wtk = wt + 512 * 512;
  const unsigned short* Wtv = wt + 2 * 512 * 512;
  const unsigned short* Wto = wt + 3 * 512 * 512;

  // ---- stage q, Q-proj (acc init = bq/8; Wq pre-scaled), extract qa ----
  stage48(q, row0, t, smem);
  __syncthreads();  // B1 (biasT/maskb also ready)
  bf16x8 qa[3][2];
  {
    f32x4 aq[3][4];
#pragma unroll
    for (int nt = 0; nt < 4; ++nt) {
      float b = biasT[0 * 512 + bidx + nt * 16];
      f32x4 b4 = {b, b, b, b};
#pragma unroll
      for (int mt = 0; mt < 3; ++mt) aq[mt][nt] = b4;
    }
    gemm_proj(smem, Wtq, w, l, lr, lk8, aq);
#pragma unroll
    for (int mt = 0; mt < 3; ++mt)
      tile_to_afrags(scr, aq[mt], lr, hi, qa[mt]);
  }
  __syncthreads();  // B2: all waves done reading staged q

  // ---- stage k, K-proj in two nt-pair passes (ack peak 24 acc regs) ----
  stage48(kin, row0, t, smem);
  __syncthreads();  // B3
  {
    bf16x8 kf[3][2];
#pragma unroll
    for (int np = 0; np < 2; ++np) {
      f32x4 ack2[3][2];
#pragma unroll
      for (int j = 0; j < 2; ++j) {
        float b = biasT[1 * 512 + bidx + (np * 2 + j) * 16];
        f32x4 b4 = {b, b, b, b};
#pragma unroll
        for (int mt = 0; mt < 3; ++mt) ack2[mt][j] = b4;
      }
      gemm_proj2(smem, Wtk, w * 4 + np * 2, l, lr, lk8, ack2);
#pragma unroll
      for (int km = 0; km < 3; ++km)
        tile_to_afrag_half(scr, ack2[km], np, lr, hi, &kf[km][np]);
    }

    // scores 48x48 (block-diagonal 3x3 kept), exact-fp32 reference mask math
#pragma unroll
    for (int km = 0; km < 3; ++km) {
      f32x4 s[3] = {};
#pragma unroll
      for (int qm = 0; qm < 3; ++qm) {
        s[qm] = __builtin_amdgcn_mfma_f32_16x16x32_bf16(qa[qm][0], kf[km][0], s[qm], 0, 0, 0);
        s[qm] = __builtin_amdgcn_mfma_f32_16x16x32_bf16(qa[qm][1], kf[km][1], s[qm], 0, 0, 0);
      }
#pragma unroll
      for (int qm = 0; qm < 3; ++qm)
#pragma unroll
        for (int r = 0; r < 4; ++r) {
          int qrow = qm * 16 + hi * 4 + r;
          int krow = km * 16 + lr;
          int qb = qrow / 3, kb2 = krow / 3;
          if (qb == kb2) pscr[qrow * 4 + (krow - kb2 * 3)] = s[qm][r];
        }
    }
    asm volatile("s_waitcnt lgkmcnt(0)" ::: "memory");
    // softmax per row; overwrite pscr with P (per-wave region, lgkm-ordered)
#pragma unroll
    for (int mt = 0; mt < 3; ++mt) {
      int row = mt * 16 + lr;
      int b = row / 3;
      int qi = row - b * 3;
      float s0 = pscr[row * 4 + 0], s1 = pscr[row * 4 + 1], s2 = pscr[row * 4 + 2];
      float m0 = (float)maskb[b * 3 + 0] * 1e9f;
      float m1 = (float)maskb[b * 3 + 1] * 1e9f;
      float m2 = (float)maskb[b * 3 + 2] * 1e9f;
      float mq = (qi == 0) ? m0 : (qi == 1) ? m1 : m2;
      float t0 = (s0 - m0) - mq;
      float t1 = (s1 - m1) - mq;
      float t2 = (s2 - m2) - mq;
      float mx = fmaxf(fmaxf(t0, t1), t2);
      float e0 = __expf(t0 - mx), e1 = __expf(t1 - mx), e2 = __expf(t2 - mx);
      float inv = 1.0f / (e0 + e1 + e2);
      asm volatile("s_waitcnt lgkmcnt(0)" ::: "memory");
      pscr[row * 4 + 0] = e0 * inv;
      pscr[row * 4 + 1] = e1 * inv;
      pscr[row * 4 + 2] = e2 * inv;
    }
  }
  __syncthreads();  // B4: all waves done reading staged k

  // ---- stage v, V-proj (acc init = bv) ----
  stage48(vin, row0, t, smem);
  __syncthreads();  // B5
  f32x4 acv[3][4];
#pragma unroll
  for (int nt = 0; nt < 4; ++nt) {
    float b = biasT[2 * 512 + bidx + nt * 16];
    f32x4 b4 = {b, b, b, b};
#pragma unroll
    for (int mt = 0; mt < 3; ++mt) acv[mt][nt] = b4;
  }
  gemm_proj(smem, Wtv, w, l, lr, lk8, acv);

  // P A-frags: convert P once to bf16 shorts, then select (no per-elem f2bf)
  bf16x8 pa[3][2];
#pragma unroll
  for (int mt = 0; mt < 3; ++mt) {
    int row = mt * 16 + lr;
    int b3 = (row / 3) * 3;
    unsigned short pb0 = f2bf(pscr[row * 4 + 0]);
    unsigned short pb1 = f2bf(pscr[row * 4 + 1]);
    unsigned short pb2 = f2bf(pscr[row * 4 + 2]);
#pragma unroll
    for (int kb = 0; kb < 2; ++kb) {
      U8 f;
#pragma unroll
      for (int e = 0; e < 8; ++e) {
        int k = kb * 32 + lk8 + e;
        int j = k - b3;
        f.u[e] = (j == 0) ? pb0 : (j == 1) ? pb1 : (j == 2) ? pb2 : (unsigned short)0;
      }
      pa[mt][kb] = f.v;
    }
  }

  __syncthreads();  // B6: all waves done reading staged v (attn overwrite ok)

  // ---- per-nt vhT extraction (col-major, packed) + PV + attn write ----
  // vh scratch: [16 lr-cols][48 k] bf16, 112 B per column (16B aligned).
#pragma unroll
  for (int nt = 0; nt < 4; ++nt) {
    // write vh[k=mt*16+hi*4+{0..3}][col=lr]: one packed b64 per mt (bias in acv)
#pragma unroll
    for (int mt = 0; mt < 3; ++mt) {
      uint2 pk;
      pk.x = cvt_pk_bf16(acv[mt][nt][0], acv[mt][nt][1]);
      pk.y = cvt_pk_bf16(acv[mt][nt][2], acv[mt][nt][3]);
      *(uint2*)(scr + lr * 112 + mt * 32 + hi * 8) = pk;
    }
    asm volatile("s_waitcnt lgkmcnt(0)" ::: "memory");
    // gather B-frags: vb[kb] = vh[32kb+8hi+e][lr], e contiguous -> b128
    // (kb=1, hi>=2 -> k>=48: redirect to offset 0; pa is 0 there)
    bf16x8 vb[2];
    vb[0] = *(const bf16x8*)(scr + lr * 112 + hi * 16);
    {
      int off1 = (hi < 2) ? (64 + hi * 16) : 0;
      vb[1] = *(const bf16x8*)(scr + lr * 112 + off1);
    }
    asm volatile("s_waitcnt lgkmcnt(0)" ::: "memory");
#pragma unroll
    for (int mt = 0; mt < 3; ++mt) {
      f32x4 po = {};
      po = __builtin_amdgcn_mfma_f32_16x16x32_bf16(pa[mt][0], vb[0], po, 0, 0, 0);
      po = __builtin_amdgcn_mfma_f32_16x16x32_bf16(pa[mt][1], vb[1], po, 0, 0, 0);
#pragma unroll
      for (int r = 0; r < 4; ++r) {
        int row = mt * 16 + hi * 4 + r;
        int col = w * 64 + nt * 16 + lr;
        *(unsigned short*)(smem + ((row * 1024 + col * 2) ^ ((row & 7) << 4))) =
            f2bf(po[r]);
      }
    }
  }
  __syncthreads();  // B7: attn ready

  // ---- out = attn @ Wo + bo (acc init = bo) ----
  f32x4 ao[3][4];
#pragma unroll
  for (int nt = 0; nt < 4; ++nt) {
    float b = biasT[3 * 512 + bidx + nt * 16];
    f32x4 b4 = {b, b, b, b};
#pragma unroll
    for (int mt = 0; mt < 3; ++mt) ao[mt][nt] = b4;
  }
  gemm_proj(smem, Wto, w, l, lr, lk8, ao);
#pragma unroll
  for (int mt = 0; mt < 3; ++mt)
#pragma unroll
    for (int nt = 0; nt < 4; ++nt)
#pragma unroll
      for (int r = 0; r < 4; ++r) {
        int grow = row0 + mt * 16 + hi * 4 + r;
        int col = w * 64 + nt * 16 + lr;
        out[(size_t)grow * 512 + col] = ao[mt][nt][r];
      }
}

extern "C" void kernel_launch(void* const* d_in, const int* in_sizes, int n_in,
                              void* d_out, int out_size, void* d_ws, size_t ws_size,
                              hipStream_t stream) {
  const float* q = (const float*)d_in[0];
  const float* k = (const float*)d_in[1];
  const float* v = (const float*)d_in[2];
  const int* mask = (const int*)d_in[3];
  const float* Wq = (const float*)d_in[4];
  const float* bq = (const float*)d_in[5];
  const float* Wk = (const float*)d_in[6];
  const float* bk = (const float*)d_in[7];
  const float* Wv = (const float*)d_in[8];
  const float* bv = (const float*)d_in[9];
  const float* Wo = (const float*)d_in[10];
  const float* bo = (const float*)d_in[11];
  float* out = (float*)d_out;
  unsigned short* wt = (unsigned short*)d_ws;  // 4 x 512x512 bf16 = 2 MB

  wtrans<<<dim3(8, 8, 4), 256, 0, stream>>>(Wq, Wk, Wv, Wo, wt);
  fused_attn<<<2048, 512, 0, stream>>>(q, k, v, mask, wt, bq, bk, bv, bo, out);
}